// Round 1
// baseline (418.652 us; speedup 1.0000x reference)
//
#include <hip/hip_runtime.h>

#define N_PTS   524288
#define P_PTS   65536
#define B_SC    8
#define SEGS    512
#define GSEG    (B_SC*SEGS)      /* 4096 */
#define HID     256

// ---------------------------------------------------------------------------
// Kernel 1: compose index chains + per-segment counts (LDS-privatized)
// ---------------------------------------------------------------------------
__global__ __launch_bounds__(256) void compose_count_kernel(
    const int* __restrict__ inv1, const int* __restrict__ inv2,
    const int* __restrict__ inv3, const int* __restrict__ p2s,
    int* __restrict__ i2, int* __restrict__ i3, int* __restrict__ cnt)
{
    __shared__ int lc[SEGS];
    const int t = threadIdx.x;
    for (int k = t; k < SEGS; k += 256) lc[k] = 0;
    __syncthreads();
    const int base = blockIdx.x * 4096;          // 4096-point chunk, one scene
    for (int i = t; i < 4096; i += 256) {
        const int q = base + i;
        const int a = inv1[q];
        const int b = inv2[a];
        i2[q] = b;
        i3[q] = inv3[b];
        atomicAdd(&lc[p2s[q]], 1);
    }
    __syncthreads();
    const int scene = base >> 16;                // P = 65536
    for (int k = t; k < SEGS; k += 256) {
        const int c = lc[k];
        if (c) atomicAdd(&cnt[scene * SEGS + k], c);
    }
}

// ---------------------------------------------------------------------------
// Kernel 2: exclusive prefix scan over 4096 counts (single block)
// ---------------------------------------------------------------------------
__global__ __launch_bounds__(1024) void scan_kernel(
    const int* __restrict__ cnt, int* __restrict__ offs, int* __restrict__ cursor)
{
    __shared__ int tmp[1024];
    const int t = threadIdx.x;
    int v[4]; int s = 0;
    #pragma unroll
    for (int i = 0; i < 4; ++i) { v[i] = cnt[t*4 + i]; s += v[i]; }
    tmp[t] = s;
    __syncthreads();
    for (int off = 1; off < 1024; off <<= 1) {
        int x = (t >= off) ? tmp[t - off] : 0;
        __syncthreads();
        tmp[t] += x;
        __syncthreads();
    }
    int excl = (t > 0) ? tmp[t-1] : 0;
    #pragma unroll
    for (int i = 0; i < 4; ++i) {
        offs[t*4 + i] = excl;
        cursor[t*4 + i] = excl;
        excl += v[i];
    }
    if (t == 1023) offs[4096] = excl;   // == N
}

// ---------------------------------------------------------------------------
// Kernel 3: scatter point ids into segment-contiguous order[]
// ---------------------------------------------------------------------------
__global__ __launch_bounds__(256) void scatter_kernel(
    const int* __restrict__ p2s, int* __restrict__ cursor, int* __restrict__ order)
{
    const int q = blockIdx.x * 256 + threadIdx.x;
    const int g = (q >> 16) * SEGS + p2s[q];
    const int pos = atomicAdd(&cursor[g], 1);
    order[pos] = q;
}

// ---------------------------------------------------------------------------
// Kernel 4: per-segment mean over all 4 levels.
// Block = one (scene,seg). 256 threads cover the concatenated 512-channel
// space as float2: t<32 -> feat0(64ch), t<64 -> feat1(64), t<128 -> feat2(128),
// t<256 -> feat3(256). Index loads software-pipelined one point ahead.
// ---------------------------------------------------------------------------
__global__ __launch_bounds__(256) void reduce_kernel(
    const float* __restrict__ f0, const float* __restrict__ f1,
    const float* __restrict__ f2, const float* __restrict__ f3,
    const int* __restrict__ i1, const int* __restrict__ i2, const int* __restrict__ i3,
    const int* __restrict__ order, const int* __restrict__ offs,
    float* __restrict__ m0, float* __restrict__ m1,
    float* __restrict__ m2, float* __restrict__ m3)
{
    const int g = blockIdx.x;
    const int start = offs[g], end = offs[g+1];
    const int t = threadIdx.x;

    int sel, coff, C;
    const float* fb;
    if (t < 32)       { sel = 0; fb = f0; C = 64;  coff = t * 2; }
    else if (t < 64)  { sel = 1; fb = f1; C = 64;  coff = (t - 32) * 2; }
    else if (t < 128) { sel = 2; fb = f2; C = 128; coff = (t - 64) * 2; }
    else              { sel = 3; fb = f3; C = 256; coff = (t - 128) * 2; }

    float ax = 0.f, ay = 0.f;
    int p = 0, a1 = 0, a2 = 0, a3 = 0;
    if (start < end) { p = order[start]; a1 = i1[p]; a2 = i2[p]; a3 = i3[p]; }
    for (int j = start; j < end; ++j) {
        // prefetch next point's indices (breaks the serial dep chain)
        int pn = 0, a1n = 0, a2n = 0, a3n = 0;
        if (j + 1 < end) { pn = order[j+1]; a1n = i1[pn]; a2n = i2[pn]; a3n = i3[pn]; }
        const int idx = (sel == 0) ? p : (sel == 1) ? a1 : (sel == 2) ? a2 : a3;
        const float2 v = *reinterpret_cast<const float2*>(fb + (size_t)idx * C + coff);
        ax += v.x; ay += v.y;
        p = pn; a1 = a1n; a2 = a2n; a3 = a3n;
    }
    const float inv = 1.0f / fmaxf((float)(end - start), 1.0f);
    ax *= inv; ay *= inv;

    float* mo = (sel == 0) ? m0 : (sel == 1) ? m1 : (sel == 2) ? m2 : m3;
    mo[(size_t)g * C + coff]     = ax;
    mo[(size_t)g * C + coff + 1] = ay;
}

// ---------------------------------------------------------------------------
// Kernel 5: [4096,C] x [C,256] GEMM + bias + LayerNorm -> out slab.
// Block = 8 rows x 256 cols; means read via uniform (scalar) float4 loads;
// W loads coalesced per channel. LN per row by one wave (4 waves, 2 rows each).
// ---------------------------------------------------------------------------
template<int C, int SLAB>
__global__ __launch_bounds__(256) void gemm_ln_kernel(
    const float* __restrict__ m, const float* __restrict__ W,
    const float* __restrict__ bias, const float* __restrict__ gma,
    const float* __restrict__ bta, float* __restrict__ out)
{
    __shared__ float sh[8][HID];
    const int t = threadIdx.x;
    const int row0 = blockIdx.x * 8;
    float acc[8] = {0.f,0.f,0.f,0.f,0.f,0.f,0.f,0.f};
    const float4* __restrict__ m4 = reinterpret_cast<const float4*>(m);

    for (int c4 = 0; c4 < C; c4 += 4) {
        const float w0 = W[(c4+0)*HID + t];
        const float w1 = W[(c4+1)*HID + t];
        const float w2 = W[(c4+2)*HID + t];
        const float w3 = W[(c4+3)*HID + t];
        #pragma unroll
        for (int r = 0; r < 8; ++r) {
            const float4 mv = m4[((row0 + r) * C + c4) >> 2];   // uniform -> s_load
            acc[r] = fmaf(mv.x, w0, acc[r]);
            acc[r] = fmaf(mv.y, w1, acc[r]);
            acc[r] = fmaf(mv.z, w2, acc[r]);
            acc[r] = fmaf(mv.w, w3, acc[r]);
        }
    }
    const float bb = bias[t];
    #pragma unroll
    for (int r = 0; r < 8; ++r) sh[r][t] = acc[r] + bb;
    __syncthreads();

    const int wave = t >> 6, lane = t & 63;
    for (int r = wave; r < 8; r += 4) {
        const float v0 = sh[r][lane      ];
        const float v1 = sh[r][lane + 64 ];
        const float v2 = sh[r][lane + 128];
        const float v3 = sh[r][lane + 192];
        float s  = v0 + v1 + v2 + v3;
        float sq = v0*v0 + v1*v1 + v2*v2 + v3*v3;
        #pragma unroll
        for (int o = 32; o > 0; o >>= 1) {
            s  += __shfl_xor(s,  o);
            sq += __shfl_xor(sq, o);
        }
        const float mean = s * (1.0f / 256.0f);
        const float var  = sq * (1.0f / 256.0f) - mean * mean;
        const float rs   = rsqrtf(var + 1e-5f);
        float* o_ = out + ((size_t)SLAB * GSEG + row0 + r) * HID;
        o_[lane      ] = (v0 - mean) * rs * gma[lane      ] + bta[lane      ];
        o_[lane + 64 ] = (v1 - mean) * rs * gma[lane + 64 ] + bta[lane + 64 ];
        o_[lane + 128] = (v2 - mean) * rs * gma[lane + 128] + bta[lane + 128];
        o_[lane + 192] = (v3 - mean) * rs * gma[lane + 192] + bta[lane + 192];
    }
}

// ---------------------------------------------------------------------------
extern "C" void kernel_launch(void* const* d_in, const int* in_sizes, int n_in,
                              void* d_out, int out_size, void* d_ws, size_t ws_size,
                              hipStream_t stream)
{
    const float* f0  = (const float*)d_in[0];
    const float* f1  = (const float*)d_in[1];
    const float* f2  = (const float*)d_in[2];
    const float* f3  = (const float*)d_in[3];
    const int* inv1  = (const int*)d_in[4];
    const int* inv2  = (const int*)d_in[5];
    const int* inv3  = (const int*)d_in[6];
    const int* p2s   = (const int*)d_in[7];
    const float* W0  = (const float*)d_in[8];
    const float* b0  = (const float*)d_in[9];
    const float* g0  = (const float*)d_in[10];
    const float* bt0 = (const float*)d_in[11];
    const float* W1  = (const float*)d_in[12];
    const float* b1  = (const float*)d_in[13];
    const float* g1  = (const float*)d_in[14];
    const float* bt1 = (const float*)d_in[15];
    const float* W2  = (const float*)d_in[16];
    const float* b2  = (const float*)d_in[17];
    const float* g2  = (const float*)d_in[18];
    const float* bt2 = (const float*)d_in[19];
    const float* W3  = (const float*)d_in[20];
    const float* b3  = (const float*)d_in[21];
    const float* g3  = (const float*)d_in[22];
    const float* bt3 = (const float*)d_in[23];
    float* out = (float*)d_out;

    char* ws = (char*)d_ws;
    int* i2     = (int*)(ws);                              // 2 MB
    int* i3     = (int*)(ws + (2u<<20));                   // 2 MB
    int* order  = (int*)(ws + (4u<<20));                   // 2 MB
    int* cnt    = (int*)(ws + (6u<<20));                   // 16 KB (pad 32)
    int* offs   = (int*)(ws + (6u<<20) + 32768);           // 16.4 KB (pad 32)
    int* cursor = (int*)(ws + (6u<<20) + 65536);           // 16 KB (pad 32)
    float* m0   = (float*)(ws + (6u<<20) + 98304);         // 1 MB
    float* m1   = m0 + (size_t)GSEG * 64;                  // 1 MB
    float* m2   = m1 + (size_t)GSEG * 64;                  // 2 MB
    float* m3   = m2 + (size_t)GSEG * 128;                 // 4 MB  (total ~14.1 MB)

    hipMemsetAsync(cnt, 0, GSEG * sizeof(int), stream);

    compose_count_kernel<<<N_PTS/4096, 256, 0, stream>>>(inv1, inv2, inv3, p2s, i2, i3, cnt);
    scan_kernel<<<1, 1024, 0, stream>>>(cnt, offs, cursor);
    scatter_kernel<<<N_PTS/256, 256, 0, stream>>>(p2s, cursor, order);
    reduce_kernel<<<GSEG, 256, 0, stream>>>(f0, f1, f2, f3, inv1, i2, i3,
                                            order, offs, m0, m1, m2, m3);

    // outs.reverse(): slab 0 = level 3 ... slab 3 = level 0
    gemm_ln_kernel<64, 3><<<GSEG/8, 256, 0, stream>>>(m0, W0, b0, g0, bt0, out);
    gemm_ln_kernel<64, 2><<<GSEG/8, 256, 0, stream>>>(m1, W1, b1, g1, bt1, out);
    gemm_ln_kernel<128,1><<<GSEG/8, 256, 0, stream>>>(m2, W2, b2, g2, bt2, out);
    gemm_ln_kernel<256,0><<<GSEG/8, 256, 0, stream>>>(m3, W3, b3, g3, bt3, out);
}

// Round 2
// 247.406 us; speedup vs baseline: 1.6922x; 1.6922x over previous
//
#include <hip/hip_runtime.h>

#define N_PTS   524288
#define P_PTS   65536
#define B_SC    8
#define SEGS    512
#define GSEG    (B_SC*SEGS)      /* 4096 */
#define HID     256

// ---------------------------------------------------------------------------
// Kernel 1: compose index chains -> packed int4 (p, i1, i2, i3) + seg counts
// ---------------------------------------------------------------------------
__global__ __launch_bounds__(256) void compose_count_kernel(
    const int* __restrict__ inv1, const int* __restrict__ inv2,
    const int* __restrict__ inv3, const int* __restrict__ p2s,
    int4* __restrict__ pk, int* __restrict__ cnt)
{
    __shared__ int lc[SEGS];
    const int t = threadIdx.x;
    for (int k = t; k < SEGS; k += 256) lc[k] = 0;
    __syncthreads();
    const int base = blockIdx.x * 4096;          // 4096-point chunk, one scene
    for (int i = t; i < 4096; i += 256) {
        const int q = base + i;
        const int a = inv1[q];
        const int b = inv2[a];
        const int c = inv3[b];
        pk[q] = make_int4(q, a, b, c);
        atomicAdd(&lc[p2s[q]], 1);
    }
    __syncthreads();
    const int scene = base >> 16;                // P = 65536
    for (int k = t; k < SEGS; k += 256) {
        const int c = lc[k];
        if (c) atomicAdd(&cnt[scene * SEGS + k], c);
    }
}

// ---------------------------------------------------------------------------
// Kernel 2: exclusive prefix scan over 4096 counts (single block)
// ---------------------------------------------------------------------------
__global__ __launch_bounds__(1024) void scan_kernel(
    const int* __restrict__ cnt, int* __restrict__ offs, int* __restrict__ cursor)
{
    __shared__ int tmp[1024];
    const int t = threadIdx.x;
    int v[4]; int s = 0;
    #pragma unroll
    for (int i = 0; i < 4; ++i) { v[i] = cnt[t*4 + i]; s += v[i]; }
    tmp[t] = s;
    __syncthreads();
    for (int off = 1; off < 1024; off <<= 1) {
        int x = (t >= off) ? tmp[t - off] : 0;
        __syncthreads();
        tmp[t] += x;
        __syncthreads();
    }
    int excl = (t > 0) ? tmp[t-1] : 0;
    #pragma unroll
    for (int i = 0; i < 4; ++i) {
        offs[t*4 + i] = excl;
        cursor[t*4 + i] = excl;
        excl += v[i];
    }
    if (t == 1023) offs[4096] = excl;   // == N
}

// ---------------------------------------------------------------------------
// Kernel 3: scatter packed indices into segment-contiguous sorted[]
// ---------------------------------------------------------------------------
__global__ __launch_bounds__(256) void scatter_kernel(
    const int* __restrict__ p2s, const int4* __restrict__ pk,
    int* __restrict__ cursor, int4* __restrict__ sorted)
{
    const int q = blockIdx.x * 256 + threadIdx.x;
    const int g = (q >> 16) * SEGS + p2s[q];
    const int pos = atomicAdd(&cursor[g], 1);
    sorted[pos] = pk[q];
}

// ---------------------------------------------------------------------------
// Kernel 4: per-segment mean over all 4 levels.
// Block = one (scene,seg). Indices staged to LDS; 128 lanes cover the
// concatenated 512-channel space as float4; 2 point-streams (t>>7) run in
// parallel; inner loop unrolled 4x -> 4 independent gathers in flight/lane.
// ---------------------------------------------------------------------------
__global__ __launch_bounds__(256) void reduce_kernel(
    const float* __restrict__ f0, const float* __restrict__ f1,
    const float* __restrict__ f2, const float* __restrict__ f3,
    const int4* __restrict__ sorted, const int* __restrict__ offs,
    float* __restrict__ m0, float* __restrict__ m1,
    float* __restrict__ m2, float* __restrict__ m3)
{
    __shared__ int4  s_idx[256];
    __shared__ float s_part[128 * 4];

    const int g = blockIdx.x;
    const int start = offs[g], end = offs[g+1];
    const int t = threadIdx.x;
    const int stream = t >> 7;       // 0 or 1
    const int t1 = t & 127;

    int sel, cshift, coff;
    const float* fb;
    float* mo;
    int C;
    if (t1 < 16)      { sel = 0; fb = f0; mo = m0; cshift = 6; C = 64;  coff = t1 * 4; }
    else if (t1 < 32) { sel = 1; fb = f1; mo = m1; cshift = 6; C = 64;  coff = (t1 - 16) * 4; }
    else if (t1 < 64) { sel = 2; fb = f2; mo = m2; cshift = 7; C = 128; coff = (t1 - 32) * 4; }
    else              { sel = 3; fb = f3; mo = m3; cshift = 8; C = 256; coff = (t1 - 64) * 4; }

    float ax = 0.f, ay = 0.f, az = 0.f, aw = 0.f;
    const int* s_idx_i = (const int*)s_idx;

    for (int cs = start; cs < end; cs += 256) {
        const int n = min(256, end - cs);
        __syncthreads();
        if (t < n) s_idx[t] = sorted[cs + t];
        __syncthreads();

        int k = stream;
        for (; k + 6 < n; k += 8) {
            const int ia = s_idx_i[(k    ) * 4 + sel];
            const int ib = s_idx_i[(k + 2) * 4 + sel];
            const int ic = s_idx_i[(k + 4) * 4 + sel];
            const int id = s_idx_i[(k + 6) * 4 + sel];
            const float4 va = *reinterpret_cast<const float4*>(fb + (((size_t)ia) << cshift) + coff);
            const float4 vb = *reinterpret_cast<const float4*>(fb + (((size_t)ib) << cshift) + coff);
            const float4 vc = *reinterpret_cast<const float4*>(fb + (((size_t)ic) << cshift) + coff);
            const float4 vd = *reinterpret_cast<const float4*>(fb + (((size_t)id) << cshift) + coff);
            ax += va.x + vb.x + vc.x + vd.x;
            ay += va.y + vb.y + vc.y + vd.y;
            az += va.z + vb.z + vc.z + vd.z;
            aw += va.w + vb.w + vc.w + vd.w;
        }
        for (; k < n; k += 2) {
            const int ia = s_idx_i[k * 4 + sel];
            const float4 va = *reinterpret_cast<const float4*>(fb + (((size_t)ia) << cshift) + coff);
            ax += va.x; ay += va.y; az += va.z; aw += va.w;
        }
    }

    __syncthreads();
    if (stream == 1) {
        float* p = &s_part[t1 * 4];
        p[0] = ax; p[1] = ay; p[2] = az; p[3] = aw;
    }
    __syncthreads();
    if (stream == 0) {
        const float* p = &s_part[t1 * 4];
        const float inv = 1.0f / fmaxf((float)(end - start), 1.0f);
        float4 o;
        o.x = (ax + p[0]) * inv;
        o.y = (ay + p[1]) * inv;
        o.z = (az + p[2]) * inv;
        o.w = (aw + p[3]) * inv;
        *reinterpret_cast<float4*>(mo + (((size_t)g) << cshift) + coff) = o;
    }
}

// ---------------------------------------------------------------------------
// Kernel 5 (fused x4): [4096,C] x [C,256] GEMM + bias + LayerNorm -> out slab.
// ---------------------------------------------------------------------------
template<int C>
__device__ __forceinline__ void gemm_ln_body(
    float (*sh)[HID], int row0,
    const float* __restrict__ m, const float* __restrict__ W,
    const float* __restrict__ bias, const float* __restrict__ gma,
    const float* __restrict__ bta, float* __restrict__ out)
{
    const int t = threadIdx.x;
    float acc[8] = {0.f,0.f,0.f,0.f,0.f,0.f,0.f,0.f};
    const float4* __restrict__ m4 = reinterpret_cast<const float4*>(m);

    for (int c4 = 0; c4 < C; c4 += 4) {
        const float w0 = W[(c4+0)*HID + t];
        const float w1 = W[(c4+1)*HID + t];
        const float w2 = W[(c4+2)*HID + t];
        const float w3 = W[(c4+3)*HID + t];
        #pragma unroll
        for (int r = 0; r < 8; ++r) {
            const float4 mv = m4[((row0 + r) * C + c4) >> 2];   // uniform -> s_load
            acc[r] = fmaf(mv.x, w0, acc[r]);
            acc[r] = fmaf(mv.y, w1, acc[r]);
            acc[r] = fmaf(mv.z, w2, acc[r]);
            acc[r] = fmaf(mv.w, w3, acc[r]);
        }
    }
    const float bb = bias[t];
    #pragma unroll
    for (int r = 0; r < 8; ++r) sh[r][t] = acc[r] + bb;
    __syncthreads();

    const int wave = t >> 6, lane = t & 63;
    for (int r = wave; r < 8; r += 4) {
        const float v0 = sh[r][lane      ];
        const float v1 = sh[r][lane + 64 ];
        const float v2 = sh[r][lane + 128];
        const float v3 = sh[r][lane + 192];
        float s  = v0 + v1 + v2 + v3;
        float sq = v0*v0 + v1*v1 + v2*v2 + v3*v3;
        #pragma unroll
        for (int o = 32; o > 0; o >>= 1) {
            s  += __shfl_xor(s,  o);
            sq += __shfl_xor(sq, o);
        }
        const float mean = s * (1.0f / 256.0f);
        const float var  = sq * (1.0f / 256.0f) - mean * mean;
        const float rs   = rsqrtf(var + 1e-5f);
        float* o_ = out + ((size_t)(row0 + r)) * HID;
        o_[lane      ] = (v0 - mean) * rs * gma[lane      ] + bta[lane      ];
        o_[lane + 64 ] = (v1 - mean) * rs * gma[lane + 64 ] + bta[lane + 64 ];
        o_[lane + 128] = (v2 - mean) * rs * gma[lane + 128] + bta[lane + 128];
        o_[lane + 192] = (v3 - mean) * rs * gma[lane + 192] + bta[lane + 192];
    }
}

__global__ __launch_bounds__(256) void gemm_ln_all_kernel(
    const float* __restrict__ m0, const float* __restrict__ m1,
    const float* __restrict__ m2, const float* __restrict__ m3,
    const float* __restrict__ W0, const float* __restrict__ b0,
    const float* __restrict__ g0, const float* __restrict__ bt0,
    const float* __restrict__ W1, const float* __restrict__ b1,
    const float* __restrict__ g1, const float* __restrict__ bt1,
    const float* __restrict__ W2, const float* __restrict__ b2,
    const float* __restrict__ g2, const float* __restrict__ bt2,
    const float* __restrict__ W3, const float* __restrict__ b3,
    const float* __restrict__ g3, const float* __restrict__ bt3,
    float* __restrict__ out)
{
    __shared__ float sh[8][HID];
    const int blk = blockIdx.x;
    const int level = blk >> 9;                 // 512 blocks per level
    const int row0 = (blk & 511) * 8;
    const size_t slab = (size_t)GSEG * HID;
    switch (level) {
        case 0: gemm_ln_body<64 >(sh, row0, m0, W0, b0, g0, bt0, out + 3*slab); break;
        case 1: gemm_ln_body<64 >(sh, row0, m1, W1, b1, g1, bt1, out + 2*slab); break;
        case 2: gemm_ln_body<128>(sh, row0, m2, W2, b2, g2, bt2, out + 1*slab); break;
        default: gemm_ln_body<256>(sh, row0, m3, W3, b3, g3, bt3, out); break;
    }
}

// ---------------------------------------------------------------------------
extern "C" void kernel_launch(void* const* d_in, const int* in_sizes, int n_in,
                              void* d_out, int out_size, void* d_ws, size_t ws_size,
                              hipStream_t stream)
{
    const float* f0  = (const float*)d_in[0];
    const float* f1  = (const float*)d_in[1];
    const float* f2  = (const float*)d_in[2];
    const float* f3  = (const float*)d_in[3];
    const int* inv1  = (const int*)d_in[4];
    const int* inv2  = (const int*)d_in[5];
    const int* inv3  = (const int*)d_in[6];
    const int* p2s   = (const int*)d_in[7];
    const float* W0  = (const float*)d_in[8];
    const float* b0  = (const float*)d_in[9];
    const float* g0  = (const float*)d_in[10];
    const float* bt0 = (const float*)d_in[11];
    const float* W1  = (const float*)d_in[12];
    const float* b1  = (const float*)d_in[13];
    const float* g1  = (const float*)d_in[14];
    const float* bt1 = (const float*)d_in[15];
    const float* W2  = (const float*)d_in[16];
    const float* b2  = (const float*)d_in[17];
    const float* g2  = (const float*)d_in[18];
    const float* bt2 = (const float*)d_in[19];
    const float* W3  = (const float*)d_in[20];
    const float* b3  = (const float*)d_in[21];
    const float* g3  = (const float*)d_in[22];
    const float* bt3 = (const float*)d_in[23];
    float* out = (float*)d_out;

    char* ws = (char*)d_ws;
    int4* pk     = (int4*)(ws);                            // 8 MB
    int4* sorted = (int4*)(ws + (8u<<20));                 // 8 MB
    int*  cnt    = (int*)(ws + (16u<<20));                 // 16 KB
    int*  offs   = (int*)(ws + (16u<<20) + 32768);         // 16.4 KB
    int*  cursor = (int*)(ws + (16u<<20) + 65536);         // 16 KB
    float* m0    = (float*)(ws + (17u<<20));               // 1 MB
    float* m1    = m0 + (size_t)GSEG * 64;                 // 1 MB
    float* m2    = m1 + (size_t)GSEG * 64;                 // 2 MB
    float* m3    = m2 + (size_t)GSEG * 128;                // 4 MB  (total ~25 MB)

    hipMemsetAsync(cnt, 0, GSEG * sizeof(int), stream);

    compose_count_kernel<<<N_PTS/4096, 256, 0, stream>>>(inv1, inv2, inv3, p2s, pk, cnt);
    scan_kernel<<<1, 1024, 0, stream>>>(cnt, offs, cursor);
    scatter_kernel<<<N_PTS/256, 256, 0, stream>>>(p2s, pk, cursor, sorted);
    reduce_kernel<<<GSEG, 256, 0, stream>>>(f0, f1, f2, f3, sorted, offs, m0, m1, m2, m3);
    gemm_ln_all_kernel<<<4*GSEG/8, 256, 0, stream>>>(
        m0, m1, m2, m3,
        W0, b0, g0, bt0, W1, b1, g1, bt1,
        W2, b2, g2, bt2, W3, b3, g3, bt3, out);
}

// Round 3
// 223.361 us; speedup vs baseline: 1.8743x; 1.1077x over previous
//
#include <hip/hip_runtime.h>

#define N_PTS   524288
#define P_PTS   65536
#define B_SC    8
#define SEGS    512
#define GSEG    (B_SC*SEGS)      /* 4096 */
#define HID     256

// ---------------------------------------------------------------------------
// Kernel 1: compose index chains -> packed int4 (p, i1, i2, i3) + seg counts.
// 512 blocks x 1024 points; 4 independent chains per thread (ILP not depth).
// ---------------------------------------------------------------------------
__global__ __launch_bounds__(256) void compose_count_kernel(
    const int* __restrict__ inv1, const int* __restrict__ inv2,
    const int* __restrict__ inv3, const int* __restrict__ p2s,
    int4* __restrict__ pk, int* __restrict__ cnt)
{
    __shared__ int lc[SEGS];
    const int t = threadIdx.x;
    lc[t] = 0; lc[t + 256] = 0;
    __syncthreads();

    const int base = blockIdx.x * 1024;
    const int q0 = base + t * 4;
    const int4 a4 = *reinterpret_cast<const int4*>(inv1 + q0);
    const int b0 = inv2[a4.x], b1 = inv2[a4.y], b2 = inv2[a4.z], b3 = inv2[a4.w];
    const int c0 = inv3[b0],   c1 = inv3[b1],   c2 = inv3[b2],   c3 = inv3[b3];
    pk[q0 + 0] = make_int4(q0 + 0, a4.x, b0, c0);
    pk[q0 + 1] = make_int4(q0 + 1, a4.y, b1, c1);
    pk[q0 + 2] = make_int4(q0 + 2, a4.z, b2, c2);
    pk[q0 + 3] = make_int4(q0 + 3, a4.w, b3, c3);

    const int4 s4 = *reinterpret_cast<const int4*>(p2s + q0);
    atomicAdd(&lc[s4.x], 1);
    atomicAdd(&lc[s4.y], 1);
    atomicAdd(&lc[s4.z], 1);
    atomicAdd(&lc[s4.w], 1);
    __syncthreads();

    const int scene = base >> 16;                // P = 65536
    const int v0 = lc[t];       if (v0) atomicAdd(&cnt[scene * SEGS + t],       v0);
    const int v1 = lc[t + 256]; if (v1) atomicAdd(&cnt[scene * SEGS + t + 256], v1);
}

// ---------------------------------------------------------------------------
// Kernel 2: exclusive prefix scan over 4096 counts (single block)
// ---------------------------------------------------------------------------
__global__ __launch_bounds__(1024) void scan_kernel(
    const int* __restrict__ cnt, int* __restrict__ offs, int* __restrict__ cursor)
{
    __shared__ int tmp[1024];
    const int t = threadIdx.x;
    int v[4]; int s = 0;
    #pragma unroll
    for (int i = 0; i < 4; ++i) { v[i] = cnt[t*4 + i]; s += v[i]; }
    tmp[t] = s;
    __syncthreads();
    for (int off = 1; off < 1024; off <<= 1) {
        int x = (t >= off) ? tmp[t - off] : 0;
        __syncthreads();
        tmp[t] += x;
        __syncthreads();
    }
    int excl = (t > 0) ? tmp[t-1] : 0;
    #pragma unroll
    for (int i = 0; i < 4; ++i) {
        offs[t*4 + i] = excl;
        cursor[t*4 + i] = excl;
        excl += v[i];
    }
    if (t == 1023) offs[4096] = excl;   // == N
}

// ---------------------------------------------------------------------------
// Kernel 3: scatter packed indices into segment-contiguous sorted[]
// ---------------------------------------------------------------------------
__global__ __launch_bounds__(256) void scatter_kernel(
    const int* __restrict__ p2s, const int4* __restrict__ pk,
    int* __restrict__ cursor, int4* __restrict__ sorted)
{
    const int q = blockIdx.x * 256 + threadIdx.x;
    const int g = (q >> 16) * SEGS + p2s[q];
    const int pos = atomicAdd(&cursor[g], 1);
    sorted[pos] = pk[q];
}

// ---------------------------------------------------------------------------
// Kernel 4 (x4 levels): per-segment mean of one level.
// Block = one (scene,seg). CL=C/4 channel-lanes, NS=256/CL point-slots,
// unroll 4 -> 4*NS points in flight. Per-level launch keeps the phase's
// gather footprint (8-32 MB) L2/L3-resident, un-polluted by other levels.
// ---------------------------------------------------------------------------
template<int C, int SEL>
__global__ __launch_bounds__(256) void reduce_level_kernel(
    const float* __restrict__ fb, const int4* __restrict__ sorted,
    const int* __restrict__ offs, float* __restrict__ mo)
{
    constexpr int CL = C / 4;        // float4 lanes per point
    constexpr int NS = 256 / CL;     // concurrent point slots
    __shared__ int    s_idx[512];
    __shared__ float4 s_red[256];

    const int g = blockIdx.x;
    const int start = offs[g], end = offs[g+1];
    const int t = threadIdx.x;
    const int slot = t / CL;
    const int coff = (t % CL) * 4;

    float ax = 0.f, ay = 0.f, az = 0.f, aw = 0.f;
    for (int cs = start; cs < end; cs += 512) {
        const int n = min(512, end - cs);
        __syncthreads();
        for (int i = t; i < n; i += 256) {
            const int4 v = sorted[cs + i];
            s_idx[i] = (SEL == 0) ? v.x : (SEL == 1) ? v.y : (SEL == 2) ? v.z : v.w;
        }
        __syncthreads();
        int k = slot;
        for (; k + 3*NS < n; k += 4*NS) {
            const int ia = s_idx[k], ib = s_idx[k + NS], ic = s_idx[k + 2*NS], id = s_idx[k + 3*NS];
            const float4 va = *reinterpret_cast<const float4*>(fb + (size_t)ia * C + coff);
            const float4 vb = *reinterpret_cast<const float4*>(fb + (size_t)ib * C + coff);
            const float4 vc = *reinterpret_cast<const float4*>(fb + (size_t)ic * C + coff);
            const float4 vd = *reinterpret_cast<const float4*>(fb + (size_t)id * C + coff);
            ax += va.x + vb.x + vc.x + vd.x;
            ay += va.y + vb.y + vc.y + vd.y;
            az += va.z + vb.z + vc.z + vd.z;
            aw += va.w + vb.w + vc.w + vd.w;
        }
        for (; k < n; k += NS) {
            const int ia = s_idx[k];
            const float4 va = *reinterpret_cast<const float4*>(fb + (size_t)ia * C + coff);
            ax += va.x; ay += va.y; az += va.z; aw += va.w;
        }
    }

    s_red[t] = make_float4(ax, ay, az, aw);
    __syncthreads();
    if (t < CL) {
        float4 s = s_red[t];
        #pragma unroll
        for (int sl = 1; sl < NS; ++sl) {
            const float4 p = s_red[sl * CL + t];
            s.x += p.x; s.y += p.y; s.z += p.z; s.w += p.w;
        }
        const float inv = 1.0f / fmaxf((float)(end - start), 1.0f);
        s.x *= inv; s.y *= inv; s.z *= inv; s.w *= inv;
        *reinterpret_cast<float4*>(mo + (size_t)g * C + t * 4) = s;
    }
}

// ---------------------------------------------------------------------------
// Kernel 5 (fused x4): [4096,C] x [C,256] GEMM + bias + LayerNorm -> out slab.
// ---------------------------------------------------------------------------
template<int C>
__device__ __forceinline__ void gemm_ln_body(
    float (*sh)[HID], int row0,
    const float* __restrict__ m, const float* __restrict__ W,
    const float* __restrict__ bias, const float* __restrict__ gma,
    const float* __restrict__ bta, float* __restrict__ out)
{
    const int t = threadIdx.x;
    float acc[8] = {0.f,0.f,0.f,0.f,0.f,0.f,0.f,0.f};
    const float4* __restrict__ m4 = reinterpret_cast<const float4*>(m);

    for (int c4 = 0; c4 < C; c4 += 4) {
        const float w0 = W[(c4+0)*HID + t];
        const float w1 = W[(c4+1)*HID + t];
        const float w2 = W[(c4+2)*HID + t];
        const float w3 = W[(c4+3)*HID + t];
        #pragma unroll
        for (int r = 0; r < 8; ++r) {
            const float4 mv = m4[((row0 + r) * C + c4) >> 2];
            acc[r] = fmaf(mv.x, w0, acc[r]);
            acc[r] = fmaf(mv.y, w1, acc[r]);
            acc[r] = fmaf(mv.z, w2, acc[r]);
            acc[r] = fmaf(mv.w, w3, acc[r]);
        }
    }
    const float bb = bias[t];
    #pragma unroll
    for (int r = 0; r < 8; ++r) sh[r][t] = acc[r] + bb;
    __syncthreads();

    const int wave = t >> 6, lane = t & 63;
    for (int r = wave; r < 8; r += 4) {
        const float v0 = sh[r][lane      ];
        const float v1 = sh[r][lane + 64 ];
        const float v2 = sh[r][lane + 128];
        const float v3 = sh[r][lane + 192];
        float s  = v0 + v1 + v2 + v3;
        float sq = v0*v0 + v1*v1 + v2*v2 + v3*v3;
        #pragma unroll
        for (int o = 32; o > 0; o >>= 1) {
            s  += __shfl_xor(s,  o);
            sq += __shfl_xor(sq, o);
        }
        const float mean = s * (1.0f / 256.0f);
        const float var  = sq * (1.0f / 256.0f) - mean * mean;
        const float rs   = rsqrtf(var + 1e-5f);
        float* o_ = out + ((size_t)(row0 + r)) * HID;
        o_[lane      ] = (v0 - mean) * rs * gma[lane      ] + bta[lane      ];
        o_[lane + 64 ] = (v1 - mean) * rs * gma[lane + 64 ] + bta[lane + 64 ];
        o_[lane + 128] = (v2 - mean) * rs * gma[lane + 128] + bta[lane + 128];
        o_[lane + 192] = (v3 - mean) * rs * gma[lane + 192] + bta[lane + 192];
    }
}

__global__ __launch_bounds__(256) void gemm_ln_all_kernel(
    const float* __restrict__ m0, const float* __restrict__ m1,
    const float* __restrict__ m2, const float* __restrict__ m3,
    const float* __restrict__ W0, const float* __restrict__ b0,
    const float* __restrict__ g0, const float* __restrict__ bt0,
    const float* __restrict__ W1, const float* __restrict__ b1,
    const float* __restrict__ g1, const float* __restrict__ bt1,
    const float* __restrict__ W2, const float* __restrict__ b2,
    const float* __restrict__ g2, const float* __restrict__ bt2,
    const float* __restrict__ W3, const float* __restrict__ b3,
    const float* __restrict__ g3, const float* __restrict__ bt3,
    float* __restrict__ out)
{
    __shared__ float sh[8][HID];
    const int blk = blockIdx.x;
    const int level = blk >> 9;                 // 512 blocks per level
    const int row0 = (blk & 511) * 8;
    const size_t slab = (size_t)GSEG * HID;
    switch (level) {
        case 0: gemm_ln_body<64 >(sh, row0, m0, W0, b0, g0, bt0, out + 3*slab); break;
        case 1: gemm_ln_body<64 >(sh, row0, m1, W1, b1, g1, bt1, out + 2*slab); break;
        case 2: gemm_ln_body<128>(sh, row0, m2, W2, b2, g2, bt2, out + 1*slab); break;
        default: gemm_ln_body<256>(sh, row0, m3, W3, b3, g3, bt3, out); break;
    }
}

// ---------------------------------------------------------------------------
extern "C" void kernel_launch(void* const* d_in, const int* in_sizes, int n_in,
                              void* d_out, int out_size, void* d_ws, size_t ws_size,
                              hipStream_t stream)
{
    const float* f0  = (const float*)d_in[0];
    const float* f1  = (const float*)d_in[1];
    const float* f2  = (const float*)d_in[2];
    const float* f3  = (const float*)d_in[3];
    const int* inv1  = (const int*)d_in[4];
    const int* inv2  = (const int*)d_in[5];
    const int* inv3  = (const int*)d_in[6];
    const int* p2s   = (const int*)d_in[7];
    const float* W0  = (const float*)d_in[8];
    const float* b0  = (const float*)d_in[9];
    const float* g0  = (const float*)d_in[10];
    const float* bt0 = (const float*)d_in[11];
    const float* W1  = (const float*)d_in[12];
    const float* b1  = (const float*)d_in[13];
    const float* g1  = (const float*)d_in[14];
    const float* bt1 = (const float*)d_in[15];
    const float* W2  = (const float*)d_in[16];
    const float* b2  = (const float*)d_in[17];
    const float* g2  = (const float*)d_in[18];
    const float* bt2 = (const float*)d_in[19];
    const float* W3  = (const float*)d_in[20];
    const float* b3  = (const float*)d_in[21];
    const float* g3  = (const float*)d_in[22];
    const float* bt3 = (const float*)d_in[23];
    float* out = (float*)d_out;

    char* ws = (char*)d_ws;
    int4* pk     = (int4*)(ws);                            // 8 MB
    int4* sorted = (int4*)(ws + (8u<<20));                 // 8 MB
    int*  cnt    = (int*)(ws + (16u<<20));                 // 16 KB
    int*  offs   = (int*)(ws + (16u<<20) + 32768);         // 16.4 KB
    int*  cursor = (int*)(ws + (16u<<20) + 65536);         // 16 KB
    float* m0    = (float*)(ws + (17u<<20));               // 1 MB
    float* m1    = m0 + (size_t)GSEG * 64;                 // 1 MB
    float* m2    = m1 + (size_t)GSEG * 64;                 // 2 MB
    float* m3    = m2 + (size_t)GSEG * 128;                // 4 MB  (total ~25 MB)

    hipMemsetAsync(cnt, 0, GSEG * sizeof(int), stream);

    compose_count_kernel<<<N_PTS/1024, 256, 0, stream>>>(inv1, inv2, inv3, p2s, pk, cnt);
    scan_kernel<<<1, 1024, 0, stream>>>(cnt, offs, cursor);
    scatter_kernel<<<N_PTS/256, 256, 0, stream>>>(p2s, pk, cursor, sorted);

    reduce_level_kernel<256,3><<<GSEG, 256, 0, stream>>>(f3, sorted, offs, m3);
    reduce_level_kernel<128,2><<<GSEG, 256, 0, stream>>>(f2, sorted, offs, m2);
    reduce_level_kernel<64, 1><<<GSEG, 256, 0, stream>>>(f1, sorted, offs, m1);
    reduce_level_kernel<64, 0><<<GSEG, 256, 0, stream>>>(f0, sorted, offs, m0);

    gemm_ln_all_kernel<<<4*GSEG/8, 256, 0, stream>>>(
        m0, m1, m2, m3,
        W0, b0, g0, bt0, W1, b1, g1, bt1,
        W2, b2, g2, bt2, W3, b3, g3, bt3, out);
}